// Round 13
// baseline (174.342 us; speedup 1.0000x reference)
//
#include <hip/hip_runtime.h>

// MLA forward: out = softmax_causal( rope(x@Wq) @ rope(x@Wk)^T / sqrt(192) ) @ (x@Wv) @ Wo + bo
// bf16 MFMA everywhere (threshold is 2% of max|ref|), fp32 accumulation.
// R13: gemm8 = R10's proven X/Y schedule + B-fragments DIRECT FROM GLOBAL (L2):
//   B is per-wave private (wave wn reads cols wn*64..+64) -> no LDS staging needed.
//   Removes 1/3 of LDS reads + 1/3 of staging writes (serial-sum model from R12:
//   tile time = MFMA + LDS-read + LDS-write even across independent blocks).
//   bX reloaded right after MM(aX,bX) (register dead), bY after MM(aY,bY) -> VGPR-neutral;
//   pre-barrier wait is counted vmcnt(4) so the B queue stays in flight.

typedef __bf16 bf16;
typedef __bf16 bf16x8 __attribute__((ext_vector_type(8)));
typedef __bf16 bf16x4 __attribute__((ext_vector_type(4)));
typedef float  f32x4  __attribute__((ext_vector_type(4)));

#define DEVI __device__ __forceinline__

static constexpr int Bc = 2, Sc = 1024, DIMc = 2048, Hc = 16;
static constexpr int NOPEc = 128, QKDc = 192, VDc = 128;
static constexpr int NQ    = Hc * QKDc;        // 3072
static constexpr int NCAT  = NQ + NQ + Hc*VDc; // 8192  [Q | K | V] per row

// ---------------- fused prep: weight transposes + x convert + rope table ----------------
__global__ __launch_bounds__(256) void k_prep(const float* __restrict__ x,
                                              const float* __restrict__ Wq, const float* __restrict__ Wk,
                                              const float* __restrict__ Wv, const float* __restrict__ Wo,
                                              bf16* __restrict__ xb, bf16* __restrict__ wcat,
                                              bf16* __restrict__ woT,
                                              float* __restrict__ cosT, float* __restrict__ sinT) {
    __shared__ float tile[64][68];
    const int yt = blockIdx.y, xt = blockIdx.x, tid = threadIdx.x;
    if (yt < 160) {   // transpose+convert: (2048 x N) fp32 -> (N x 2048) bf16
        const float* src; bf16* dst; int N, n0;
        if (yt < 48)       { src = Wq; N = 3072; n0 = yt * 64;         dst = wcat; }
        else if (yt < 96)  { src = Wk; N = 3072; n0 = (yt - 48) * 64;  dst = wcat + (size_t)3072 * 2048; }
        else if (yt < 128) { src = Wv; N = 2048; n0 = (yt - 96) * 64;  dst = wcat + (size_t)6144 * 2048; }
        else               { src = Wo; N = 2048; n0 = (yt - 128) * 64; dst = woT; }
        int k0 = xt * 64;
        int tr = tid >> 4, tc = (tid & 15) * 4;
#pragma unroll
        for (int i = 0; i < 4; i++) {
            int r = tr + i * 16;
            float4 v = *(const float4*)(src + (size_t)(k0 + r) * N + n0 + tc);
            tile[r][tc+0] = v.x; tile[r][tc+1] = v.y; tile[r][tc+2] = v.z; tile[r][tc+3] = v.w;
        }
        __syncthreads();
#pragma unroll
        for (int i = 0; i < 4; i++) {
            int n = tr + i * 16;
            bf16x4 o;
#pragma unroll
            for (int j = 0; j < 4; j++) o[j] = (bf16)tile[tc + j][n];
            *(bf16x4*)(dst + (size_t)(n0 + n) * 2048 + k0 + tc) = o;
        }
    } else if (yt < 224) {   // x fp32 -> bf16, 8 elems/thread
        int i = (((yt - 160) * 32 + xt) * 256 + tid) * 8;
        float4 a = *(const float4*)(x + i);
        float4 b = *(const float4*)(x + i + 4);
        bf16x8 o;
        o[0]=(bf16)a.x; o[1]=(bf16)a.y; o[2]=(bf16)a.z; o[3]=(bf16)a.w;
        o[4]=(bf16)b.x; o[5]=(bf16)b.y; o[6]=(bf16)b.z; o[7]=(bf16)b.w;
        *(bf16x8*)(xb + i) = o;
    } else {   // rope table: S*32 entries
#pragma unroll
        for (int p = 0; p < 4; p++) {
            int idx = p * 8192 + xt * 256 + tid;
            int pos = idx >> 5, i = idx & 31;
            float theta = expf(-(float)i * (9.210340371976184f / 32.0f)); // 10000^(-i/32)
            float ang = (float)pos * theta;
            cosT[idx] = cosf(ang);
            sinT[idx] = sinf(ang);
        }
    }
}

// ---------------- RoPE (Q+K) and V^T in one launch (disjoint qkv sections) ----------------
__global__ __launch_bounds__(256) void k_ropevt(bf16* __restrict__ qkv, const float* __restrict__ cosT,
                                                const float* __restrict__ sinT, bf16* __restrict__ vT) {
    const int bidx = blockIdx.x, tid = threadIdx.x;
    if (bidx < 2048) {   // rope on Q (bidx<1024) or K section
        int secbase = (bidx >= 1024) ? NQ : 0;
        int idx = (bidx & 1023) * 256 + tid;
        int g = idx & 7, h = (idx >> 3) & 15, row = idx >> 7;
        int s = row & (Sc - 1);
        bf16* p = qkv + (size_t)row * NCAT + secbase + h * QKDc + NOPEc + g * 8;
        bf16x8 v = *(bf16x8*)p;
        const float* cp = cosT + s * 32 + g * 4;
        const float* sp = sinT + s * 32 + g * 4;
#pragma unroll
        for (int q = 0; q < 4; q++) {
            float x0 = (float)v[2*q], x1 = (float)v[2*q+1];
            float c = cp[q], sn = sp[q];
            v[2*q]   = (bf16)(x0 * c - x1 * sn);
            v[2*q+1] = (bf16)(x1 * c + x0 * sn);
        }
        *(bf16x8*)p = v;
    } else {             // V^T
        __shared__ bf16 tile[64][72];
        const int vb = bidx - 2048;
        const int st = vb & 15, dt = (vb >> 4) & 1, bh = vb >> 5;
        const int b = bh >> 4, h = bh & 15;
        int r = tid >> 3, c8 = (tid & 7) * 8;
        const bf16* src = qkv + (size_t)(b * Sc + st * 64) * NCAT + 2 * NQ + h * VDc + dt * 64;
#pragma unroll
        for (int i = 0; i < 2; i++) {
            int rr = r + i * 32;   // s_local
            *(bf16x8*)&tile[rr][c8] = *(const bf16x8*)(src + (size_t)rr * NCAT + c8);
        }
        __syncthreads();
        bf16* dst = vT + ((size_t)bh * 128 + dt * 64) * Sc + st * 64;
#pragma unroll
        for (int i = 0; i < 2; i++) {
            int rr = r + i * 32;   // vd_local
            bf16x8 o;
#pragma unroll
            for (int j = 0; j < 8; j++) o[j] = tile[c8 + j][rr];
            *(bf16x8*)(dst + (size_t)rr * Sc + c8) = o;
        }
    }
}

// ---------------- async global->LDS, 16B per lane ----------------
DEVI void gload16(const bf16* g, bf16* l) {
    __builtin_amdgcn_global_load_lds((const __attribute__((address_space(1))) void*)g,
                                     (__attribute__((address_space(3))) void*)l, 16, 0, 0);
}

// ================= 256x256 GEMM (QKV projection): A via LDS (R10 schedule), B direct from L2 =================
__global__ __launch_bounds__(512, 2) void k_gemm8(const bf16* __restrict__ A, const bf16* __restrict__ Bt,
                                                  bf16* __restrict__ C, int N, int K, int NCT) {
    __shared__ __align__(16) bf16 lds[2][2][256 * 32];  // [buf][ks][A slice] = 64 KiB (A only)
    const int tid = threadIdx.x;
    const int l = tid & 63, wid = tid >> 6;
    const int lg = l >> 4, lc = l & 15;
    const int wm = wid >> 2, wn = wid & 3;          // 2x4 wave grid; wave owns 128x64
    const int bid = blockIdx.x;
    const int xcd = bid & 7, g = bid >> 3;
    const int per = NCT >> 3;                        // col-panels per XCD
    const int rt = g & 7, ct = xcd * per + (g >> 3); // 8 row-tiles, panels pinned to XCD
    const int row0 = rt * 256, col0 = ct * 256;
    const int NT = K >> 6;

    const bf16* Abase = A  + (size_t)row0 * K;
    // per-lane B base: wave's columns col0+wn*64+fc*16+lc, k-offset lg*8
    const bf16* Bl = Bt + (size_t)(col0 + wn * 64 + lc) * K + lg * 8;

    size_t srcoff0, srcoff1;
    int ldsoff0, ldsoff1;
    {
        int li0 = tid,        r0 = li0 >> 2, u0 = li0 & 3;
        int li1 = 512 + tid,  r1 = li1 >> 2, u1 = li1 & 3;
        srcoff0 = (size_t)r0 * K + ((u0 ^ ((r0 >> 1) & 3)) << 3);  ldsoff0 = li0 * 8;
        srcoff1 = (size_t)r1 * K + ((u1 ^ ((r1 >> 1) & 3)) << 3);  ldsoff1 = li1 * 8;
    }

#define STAGEA(ks, ktile, buf) { \
    const bf16* ga_ = Abase + (ktile) * 64 + (ks) * 32; \
    gload16(ga_ + srcoff0, &lds[buf][ks][0] + ldsoff0); \
    gload16(ga_ + srcoff1, &lds[buf][ks][0] + ldsoff1); }

// B fragment loads straight from global (L2): frag fc, k-slice ks of tile kt
#define LOADB(dst, ks, ktile) { _Pragma("unroll") \
    for (int fc_ = 0; fc_ < 4; fc_++) \
        dst[fc_] = *(const bf16x8*)(Bl + (size_t)(fc_ * 16) * K + (ktile) * 64 + (ks) * 32); }

#define RD_A8(dst, P) { _Pragma("unroll") \
    for (int i_ = 0; i_ < 8; i_++) { \
        int row_ = wm * 128 + i_ * 16 + lc; \
        dst[i_] = *(const bf16x8*)((P) + row_ * 32 + ((lg ^ ((row_ >> 1) & 3)) << 3)); } }
#define MM32(Av, Bv) { _Pragma("unroll") \
    for (int i_ = 0; i_ < 8; i_++) _Pragma("unroll") \
        for (int fc_ = 0; fc_ < 4; fc_++) \
            acc[i_][fc_] = __builtin_amdgcn_mfma_f32_16x16x32_bf16(Av[i_], Bv[fc_], acc[i_][fc_], 0, 0, 0); }
#define BAR() { __builtin_amdgcn_s_barrier(); asm volatile("" ::: "memory"); }

    f32x4 acc[8][4] = {};
    bf16x8 aX[8], aY[8], bX[4], bY[4];

    // prologue: stage A(tile0); load B(tile0) both slices; drain A; pre-read aX
    STAGEA(0, 0, 0); STAGEA(1, 0, 0);
    LOADB(bX, 0, 0); LOADB(bY, 1, 0);
    asm volatile("s_waitcnt vmcnt(0)" ::: "memory");
    BAR();
    RD_A8(aX, &lds[0][0][0]);

    for (int kt = 0; kt < NT; ++kt) {
        const int cur = kt & 1, nxt = cur ^ 1;
        const bool notlast = (kt + 1 < NT);
        // stage A(kt+1): 4 gload_lds (oldest in VMEM queue this tile)
        if (notlast) { STAGEA(0, kt + 1, nxt); STAGEA(1, kt + 1, nxt); }
        RD_A8(aY, &lds[cur][1][0]);                    // 8 ds_reads, covered by MM(aX,bX)
        __builtin_amdgcn_s_setprio(1);
        MM32(aX, bX);
        __builtin_amdgcn_s_setprio(0);
        if (notlast) LOADB(bX, 0, kt + 1);             // bX dead; 4 vmem, consumed next tile
        if (notlast) {
            asm volatile("s_waitcnt lgkmcnt(0)" ::: "memory");   // cur reads in regs
            asm volatile("s_waitcnt vmcnt(4)" ::: "memory");     // A-stage (oldest 4) landed; B stays in flight
            BAR();                                               // publish nxt, free cur
            RD_A8(aX, &lds[nxt][0][0]);                          // covered by MM(aY,bY)
        } else {
            asm volatile("s_waitcnt lgkmcnt(0)" ::: "memory");
        }
        __builtin_amdgcn_s_setprio(1);
        MM32(aY, bY);
        __builtin_amdgcn_s_setprio(0);
        if (notlast) LOADB(bY, 1, kt + 1);             // bY dead; consumed next tile
    }
#undef STAGEA
#undef LOADB
#undef RD_A8
#undef MM32
#undef BAR
    // epilogue: D row = (lane>>4)*4 + reg, col = lane&15  [m89/m91]
#pragma unroll
    for (int m = 0; m < 8; m++)
#pragma unroll
        for (int fc = 0; fc < 4; fc++)
#pragma unroll
            for (int j = 0; j < 4; j++) {
                int r = row0 + wm * 128 + m * 16 + lg * 4 + j;
                int c = col0 + wn * 64 + fc * 16 + lc;
                C[(size_t)r * N + c] = (bf16)acc[m][fc][j];
            }
}

// ================= 128x128 8-wave phase-pipelined GEMM (out-projection, fp32 out + bias) =================
__global__ __launch_bounds__(512, 2) void k_gemmO(const bf16* __restrict__ A, const bf16* __restrict__ Bt,
                                                  float* __restrict__ C, const float* __restrict__ bias,
                                                  int N, int K) {
    __shared__ __align__(16) bf16 lds[2][2][2][128 * 32];  // [buf][A/B][ks][slice] = 64 KiB
    const int tid = threadIdx.x;
    const int l = tid & 63, wid = tid >> 6;
    const int lg = l >> 4, lc = l & 15;
    const int wm = wid >> 2, wn = wid & 3;          // 2x4 wave grid; wave owns 64x32
    const int bid = blockIdx.x;
    const int xcd = bid & 7, g = bid >> 3;
    const int rt = g & 15, ct = xcd * 2 + (g >> 4); // 16 row-tiles, 2 col-panels per XCD
    const int row0 = rt * 128, col0 = ct * 128;
    const int NT = K >> 6;

    const bf16* Abase = A  + (size_t)row0 * K;
    const bf16* Bbase = Bt + (size_t)col0 * K;

    size_t srcoff; int ldsoff;
    {
        int r0 = tid >> 2, u0 = tid & 3;
        srcoff = (size_t)r0 * K + ((u0 ^ ((r0 >> 1) & 3)) << 3);
        ldsoff = tid * 8;
    }

#define STAGEO(ab, ks, ktile, buf) { \
    const bf16* gb_ = ((ab) ? Bbase : Abase) + (ktile) * 64 + (ks) * 32; \
    gload16(gb_ + srcoff, &lds[buf][ab][ks][0] + ldsoff); }

    f32x4 acc[4][2] = {};

    STAGEO(0, 0, 0, 0); STAGEO(1, 0, 0, 0); STAGEO(0, 1, 0, 0); STAGEO(1, 1, 0, 0);
    asm volatile("s_waitcnt vmcnt(2)" ::: "memory");
    __builtin_amdgcn_s_barrier();
    asm volatile("" ::: "memory");

    for (int kt = 0; kt < NT; ++kt) {
        const int cur = kt & 1, nxt = cur ^ 1;
        const bool notlast = (kt + 1 < NT);
#pragma unroll
        for (int ph = 0; ph < 2; ph++) {
            const bf16* As_ = &lds[cur][0][ph][0];
            const bf16* Bs_ = &lds[cur][1][ph][0];
            bf16x8 aF[4], bB[2];
#pragma unroll
            for (int n = 0; n < 2; n++) {
                int row = wn * 32 + n * 16 + lc;
                bB[n] = *(const bf16x8*)(Bs_ + row * 32 + ((lg ^ ((row >> 1) & 3)) << 3));
            }
#pragma unroll
            for (int m = 0; m < 4; m++) {
                int row = wm * 64 + m * 16 + lc;
                aF[m] = *(const bf16x8*)(As_ + row * 32 + ((lg ^ ((row >> 1) & 3)) << 3));
            }
            if (notlast) {
                if (ph == 0) { STAGEO(0, 0, kt + 1, nxt); STAGEO(1, 0, kt + 1, nxt); }
                else         { STAGEO(0, 1, kt + 1, nxt); STAGEO(1, 1, kt + 1, nxt); }
            }
            __builtin_amdgcn_s_barrier();
            asm volatile("" ::: "memory");
            __builtin_amdgcn_s_setprio(1);
#pragma unroll
            for (int m = 0; m < 4; m++)
#pragma unroll
                for (int n = 0; n < 2; n++)
                    acc[m][n] = __builtin_amdgcn_mfma_f32_16x16x32_bf16(aF[m], bB[n], acc[m][n], 0, 0, 0);
            __builtin_amdgcn_s_setprio(0);
            if (notlast)          asm volatile("s_waitcnt vmcnt(2)" ::: "memory");
            else if (ph == 0)     asm volatile("s_waitcnt vmcnt(0)" ::: "memory");
            __builtin_amdgcn_s_barrier();
            asm volatile("" ::: "memory");
        }
    }
#undef STAGEO
#pragma unroll
    for (int m = 0; m < 4; m++)
#pragma unroll
        for (int n = 0; n < 2; n++)
#pragma unroll
            for (int j = 0; j < 4; j++) {
                int r = row0 + wm * 64 + m * 16 + lg * 4 + j;
                int c = col0 + wn * 32 + n * 16 + lc;
                C[(size_t)r * N + c] = acc[m][n][j] + bias[c];
            }
}

// ---------------- flash attention: K/V cooperatively LDS-staged, pipelined ----------------
__global__ __launch_bounds__(256, 3) void k_attn(const bf16* __restrict__ qkv, const bf16* __restrict__ vT,
                                                 bf16* __restrict__ cv) {
    const int bid = blockIdx.x;
    const int xcd = bid & 7, g = bid >> 3;
    const int qt = (g & 32) ? (g & 15) : (15 - (g & 15));  // balanced pairing
    const int bh = xcd + 8 * (g >> 4);     // all q-tiles of a bh pinned to one XCD
    const int b = bh >> 4, h = bh & 15;
    const int tid = threadIdx.x, l = tid & 63, w = tid >> 6;
    const int lg = l >> 4, lc = l & 15;
    __shared__ __align__(16) bf16 Ks[64 * 192];     // 24576 B
    __shared__ __align__(16) bf16 Vs[128 * 64];     // 16384 B
    __shared__ __align__(16) bf16 Pl[4][16][72];    //  9216 B
    const bf16* Qb = qkv + (size_t)b * Sc * NCAT + h * QKDc;
    const bf16* Kb = Qb + NQ;
    const bf16* Vt = vT + (size_t)bh * 128 * Sc;    // [128][1024]

    int sK[6];
#pragma unroll
    for (int r = 0; r < 6; r++) {
        int li = r * 256 + tid;
        int row = li / 24, c16 = li - row * 24;
        sK[r] = row * NCAT + ((c16 ^ (row & 7)) * 8);
    }
    int sV[4];
#pragma unroll
    for (int r = 0; r < 4; r++) {
        int li = r * 256 + tid;
        int row = li >> 3, c16 = li & 7;
        sV[r] = row * Sc + ((c16 ^ (row & 7)) * 8);
    }
    const int swz = lc & 7;

    bf16x8 qF[6];
    const int qrow = qt * 64 + w * 16 + lc;
#pragma unroll
    for (int kc = 0; kc < 6; kc++) qF[kc] = *(const bf16x8*)(Qb + (size_t)qrow * NCAT + kc * 32 + lg * 8);

    f32x4 acc[8] = {};
    float mrow[4] = {-1e30f, -1e30f, -1e30f, -1e30f};
    float lsum[4] = {0.f, 0.f, 0.f, 0.f};
    const float scale = 0.07216878364870323f;  // 192^-0.5

#pragma unroll
    for (int r = 0; r < 6; r++) gload16(Kb + sK[r], Ks + (r * 256 + tid) * 8);

    for (int c = 0; c <= qt; ++c) {
        const int t0 = c * 64;
        __syncthreads();   // B1: drains vmcnt -> K[c] staged
#pragma unroll
        for (int r = 0; r < 4; r++) gload16(Vt + t0 + sV[r], Vs + (r * 256 + tid) * 8);
        f32x4 sc[4] = {};
#pragma unroll
        for (int nt = 0; nt < 4; nt++)
#pragma unroll
            for (int kc = 0; kc < 6; kc++) {
                bf16x8 kf = *(const bf16x8*)(Ks + (nt * 16 + lc) * 192 + (((kc * 4 + lg) ^ swz) * 8));
                sc[nt] = __builtin_amdgcn_mfma_f32_16x16x32_bf16(qF[kc], kf, sc[nt], 0, 0, 0);
            }
        __syncthreads();   // B2: K[c] reads done; drains vmcnt -> V[c] staged
        if (c < qt) {
#pragma unroll
            for (int r = 0; r < 6; r++) gload16(Kb + (size_t)(t0 + 64) * NCAT + sK[r], Ks + (r * 256 + tid) * 8);
        }
        float p[4][4];
        float cmax[4] = {-1e30f, -1e30f, -1e30f, -1e30f};
        const bool diag = (c == qt);
#pragma unroll
        for (int nt = 0; nt < 4; nt++)
#pragma unroll
            for (int j = 0; j < 4; j++) {
                float v = sc[nt][j] * scale;
                if (diag) {
                    int tg = t0 + nt * 16 + lc;
                    int rg = qt * 64 + w * 16 + lg * 4 + j;
                    if (tg > rg) v = -1e9f;
                }
                p[nt][j] = v;
                cmax[j] = fmaxf(cmax[j], v);
            }
#pragma unroll
        for (int j = 0; j < 4; j++)
#pragma unroll
            for (int d = 1; d < 16; d <<= 1) cmax[j] = fmaxf(cmax[j], __shfl_xor(cmax[j], d));
        float f[4];
#pragma unroll
        for (int j = 0; j < 4; j++) {
            float nm = fmaxf(mrow[j], cmax[j]);
            f[j] = __expf(mrow[j] - nm);
            mrow[j] = nm;
        }
        float psum[4] = {0.f, 0.f, 0.f, 0.f};
#pragma unroll
        for (int nt = 0; nt < 4; nt++)
#pragma unroll
            for (int j = 0; j < 4; j++) {
                p[nt][j] = __expf(p[nt][j] - mrow[j]);
                psum[j] += p[nt][j];
            }
#pragma unroll
        for (int j = 0; j < 4; j++) {
#pragma unroll
            for (int d = 1; d < 16; d <<= 1) psum[j] += __shfl_xor(psum[j], d);
            lsum[j] = lsum[j] * f[j] + psum[j];
        }
#pragma unroll
        for (int n = 0; n < 8; n++)
#pragma unroll
            for (int j = 0; j < 4; j++) acc[n][j] *= f[j];
#pragma unroll
        for (int nt = 0; nt < 4; nt++)
#pragma unroll
            for (int j = 0; j < 4; j++)
                Pl[w][lg * 4 + j][nt * 16 + lc] = (bf16)p[nt][j];
#pragma unroll
        for (int ks = 0; ks < 2; ks++) {
            bf16x8 aP = *(const bf16x8*)(&Pl[w][lc][ks * 32 + lg * 8]);
#pragma unroll
            for (int n = 0; n < 8; n++) {
                bf16x8 bV = *(const bf16x8*)(Vs + (n * 16 + lc) * 64 + (((ks * 4 + lg) ^ swz) * 8));
                acc[n] = __builtin_amdgcn_mfma_f32_16x16x32_bf16(aP, bV, acc[n], 0, 0, 0);
            }
        }
    }
#pragma unroll
    for (int j = 0; j < 4; j++) {
        float inv = 1.0f / lsum[j];
        int r = qt * 64 + w * 16 + lg * 4 + j;
#pragma unroll
        for (int n = 0; n < 8; n++) {
            float v = acc[n][j] * inv;
            cv[((size_t)(b * Sc + r) * Hc + h) * VDc + n * 16 + lc] = (bf16)v;
        }
    }
}

// ---------------- launch ----------------
extern "C" void kernel_launch(void* const* d_in, const int* in_sizes, int n_in,
                              void* d_out, int out_size, void* d_ws, size_t ws_size,
                              hipStream_t stream) {
    const float* x  = (const float*)d_in[0];
    const float* Wq = (const float*)d_in[1];
    const float* Wk = (const float*)d_in[2];
    const float* Wv = (const float*)d_in[3];
    const float* Wo = (const float*)d_in[4];
    const float* bo = (const float*)d_in[5];
    float* out = (float*)d_out;
    char* ws = (char*)d_ws;

    // workspace layout (bytes)
    bf16*  wcat = (bf16*)(ws + 0);           // 8192x2048 bf16 = 33554432
    bf16*  woT  = (bf16*)(ws + 33554432);    // 2048x2048 bf16 =  8388608
    bf16*  xb   = (bf16*)(ws + 41943040);    // 2048x2048 bf16 =  8388608
    bf16*  qkvb = (bf16*)(ws + 50331648);    // 2048x8192 bf16 = 33554432
    bf16*  cvb  = (bf16*)(ws + 83886080);    // 2048x2048 bf16 =  8388608
    bf16*  vTb  = (bf16*)(ws + 92274688);    // 32x128x1024 bf16 = 8388608
    float* cosT = (float*)(ws + 100663296);  // 1024x32 f32    =   131072
    float* sinT = (float*)(ws + 100794368);  // 1024x32 f32    =   131072

    k_prep<<<dim3(32, 225), 256, 0, stream>>>(x, Wq, Wk, Wv, Wo, xb, wcat, woT, cosT, sinT);
    // fused QKV projection: (2048x2048) x (8192x2048)^T -> (2048x8192) bf16
    k_gemm8<<<256, 512, 0, stream>>>(xb, wcat, qkvb, NCAT, DIMc, NCAT / 256);
    k_ropevt<<<3072, 256, 0, stream>>>(qkvb, cosT, sinT, vTb); // rope Q+K, and V^T
    k_attn<<<512, 256, 0, stream>>>(qkvb, vTb, cvb);
    // output projection with bias: (2048x2048) x (2048x2048)^T -> fp32 out
    k_gemmO<<<256, 512, 0, stream>>>(cvb, woT, out, bo, DIMc, DIMc);
}

// Round 14
// 157.590 us; speedup vs baseline: 1.1063x; 1.1063x over previous
//
#include <hip/hip_runtime.h>

// MLA forward: out = softmax_causal( rope(x@Wq) @ rope(x@Wk)^T / sqrt(192) ) @ (x@Wv) @ Wo + bo
// bf16 MFMA everywhere (threshold is 2% of max|ref|), fp32 accumulation.
// R14: REVERT gemm8 to R10's measured-best X/Y software pipeline (70.3us, 40% MfmaUtil).
//   R13's B-direct-from-L2 regressed (scattered VMEM in consume chain); R11 role-split
//   spilled; R12 occupancy-2 was neutral. Serial-sum model (MFMA + LDS-read + LDS-write)
//   stands as this schedule family's floor. k_ropevt merge (R12) kept.

typedef __bf16 bf16;
typedef __bf16 bf16x8 __attribute__((ext_vector_type(8)));
typedef __bf16 bf16x4 __attribute__((ext_vector_type(4)));
typedef float  f32x4  __attribute__((ext_vector_type(4)));

#define DEVI __device__ __forceinline__

static constexpr int Bc = 2, Sc = 1024, DIMc = 2048, Hc = 16;
static constexpr int NOPEc = 128, QKDc = 192, VDc = 128;
static constexpr int NQ    = Hc * QKDc;        // 3072
static constexpr int NCAT  = NQ + NQ + Hc*VDc; // 8192  [Q | K | V] per row

// ---------------- fused prep: weight transposes + x convert + rope table ----------------
__global__ __launch_bounds__(256) void k_prep(const float* __restrict__ x,
                                              const float* __restrict__ Wq, const float* __restrict__ Wk,
                                              const float* __restrict__ Wv, const float* __restrict__ Wo,
                                              bf16* __restrict__ xb, bf16* __restrict__ wcat,
                                              bf16* __restrict__ woT,
                                              float* __restrict__ cosT, float* __restrict__ sinT) {
    __shared__ float tile[64][68];
    const int yt = blockIdx.y, xt = blockIdx.x, tid = threadIdx.x;
    if (yt < 160) {   // transpose+convert: (2048 x N) fp32 -> (N x 2048) bf16
        const float* src; bf16* dst; int N, n0;
        if (yt < 48)       { src = Wq; N = 3072; n0 = yt * 64;         dst = wcat; }
        else if (yt < 96)  { src = Wk; N = 3072; n0 = (yt - 48) * 64;  dst = wcat + (size_t)3072 * 2048; }
        else if (yt < 128) { src = Wv; N = 2048; n0 = (yt - 96) * 64;  dst = wcat + (size_t)6144 * 2048; }
        else               { src = Wo; N = 2048; n0 = (yt - 128) * 64; dst = woT; }
        int k0 = xt * 64;
        int tr = tid >> 4, tc = (tid & 15) * 4;
#pragma unroll
        for (int i = 0; i < 4; i++) {
            int r = tr + i * 16;
            float4 v = *(const float4*)(src + (size_t)(k0 + r) * N + n0 + tc);
            tile[r][tc+0] = v.x; tile[r][tc+1] = v.y; tile[r][tc+2] = v.z; tile[r][tc+3] = v.w;
        }
        __syncthreads();
#pragma unroll
        for (int i = 0; i < 4; i++) {
            int n = tr + i * 16;
            bf16x4 o;
#pragma unroll
            for (int j = 0; j < 4; j++) o[j] = (bf16)tile[tc + j][n];
            *(bf16x4*)(dst + (size_t)(n0 + n) * 2048 + k0 + tc) = o;
        }
    } else if (yt < 224) {   // x fp32 -> bf16, 8 elems/thread
        int i = (((yt - 160) * 32 + xt) * 256 + tid) * 8;
        float4 a = *(const float4*)(x + i);
        float4 b = *(const float4*)(x + i + 4);
        bf16x8 o;
        o[0]=(bf16)a.x; o[1]=(bf16)a.y; o[2]=(bf16)a.z; o[3]=(bf16)a.w;
        o[4]=(bf16)b.x; o[5]=(bf16)b.y; o[6]=(bf16)b.z; o[7]=(bf16)b.w;
        *(bf16x8*)(xb + i) = o;
    } else {   // rope table: S*32 entries
#pragma unroll
        for (int p = 0; p < 4; p++) {
            int idx = p * 8192 + xt * 256 + tid;
            int pos = idx >> 5, i = idx & 31;
            float theta = expf(-(float)i * (9.210340371976184f / 32.0f)); // 10000^(-i/32)
            float ang = (float)pos * theta;
            cosT[idx] = cosf(ang);
            sinT[idx] = sinf(ang);
        }
    }
}

// ---------------- RoPE (Q+K) and V^T in one launch (disjoint qkv sections) ----------------
__global__ __launch_bounds__(256) void k_ropevt(bf16* __restrict__ qkv, const float* __restrict__ cosT,
                                                const float* __restrict__ sinT, bf16* __restrict__ vT) {
    const int bidx = blockIdx.x, tid = threadIdx.x;
    if (bidx < 2048) {   // rope on Q (bidx<1024) or K section
        int secbase = (bidx >= 1024) ? NQ : 0;
        int idx = (bidx & 1023) * 256 + tid;
        int g = idx & 7, h = (idx >> 3) & 15, row = idx >> 7;
        int s = row & (Sc - 1);
        bf16* p = qkv + (size_t)row * NCAT + secbase + h * QKDc + NOPEc + g * 8;
        bf16x8 v = *(bf16x8*)p;
        const float* cp = cosT + s * 32 + g * 4;
        const float* sp = sinT + s * 32 + g * 4;
#pragma unroll
        for (int q = 0; q < 4; q++) {
            float x0 = (float)v[2*q], x1 = (float)v[2*q+1];
            float c = cp[q], sn = sp[q];
            v[2*q]   = (bf16)(x0 * c - x1 * sn);
            v[2*q+1] = (bf16)(x1 * c + x0 * sn);
        }
        *(bf16x8*)p = v;
    } else {             // V^T
        __shared__ bf16 tile[64][72];
        const int vb = bidx - 2048;
        const int st = vb & 15, dt = (vb >> 4) & 1, bh = vb >> 5;
        const int b = bh >> 4, h = bh & 15;
        int r = tid >> 3, c8 = (tid & 7) * 8;
        const bf16* src = qkv + (size_t)(b * Sc + st * 64) * NCAT + 2 * NQ + h * VDc + dt * 64;
#pragma unroll
        for (int i = 0; i < 2; i++) {
            int rr = r + i * 32;   // s_local
            *(bf16x8*)&tile[rr][c8] = *(const bf16x8*)(src + (size_t)rr * NCAT + c8);
        }
        __syncthreads();
        bf16* dst = vT + ((size_t)bh * 128 + dt * 64) * Sc + st * 64;
#pragma unroll
        for (int i = 0; i < 2; i++) {
            int rr = r + i * 32;   // vd_local
            bf16x8 o;
#pragma unroll
            for (int j = 0; j < 8; j++) o[j] = tile[c8 + j][rr];
            *(bf16x8*)(dst + (size_t)rr * Sc + c8) = o;
        }
    }
}

// ---------------- async global->LDS, 16B per lane ----------------
DEVI void gload16(const bf16* g, bf16* l) {
    __builtin_amdgcn_global_load_lds((const __attribute__((address_space(1))) void*)g,
                                     (__attribute__((address_space(3))) void*)l, 16, 0, 0);
}

// ================= 256x256 GEMM (QKV projection), X/Y software-pipelined (R10, measured best) =================
__global__ __launch_bounds__(512, 2) void k_gemm8(const bf16* __restrict__ A, const bf16* __restrict__ Bt,
                                                  bf16* __restrict__ C, int N, int K, int NCT) {
    __shared__ __align__(16) bf16 lds[2][2][2][256 * 32];  // [buf][A=0/B=1][ks][slice] = 128 KiB
    const int tid = threadIdx.x;
    const int l = tid & 63, wid = tid >> 6;
    const int lg = l >> 4, lc = l & 15;
    const int wm = wid >> 2, wn = wid & 3;          // 2x4 wave grid; wave owns 128x64
    const int bid = blockIdx.x;
    const int xcd = bid & 7, g = bid >> 3;
    const int per = NCT >> 3;                        // col-panels per XCD
    const int rt = g & 7, ct = xcd * per + (g >> 3); // 8 row-tiles, panels pinned to XCD
    const int row0 = rt * 256, col0 = ct * 256;
    const int NT = K >> 6;

    const bf16* Abase = A  + (size_t)row0 * K;
    const bf16* Bbase = Bt + (size_t)col0 * K;

    size_t srcoff0, srcoff1;
    int ldsoff0, ldsoff1;
    {
        int li0 = tid,        r0 = li0 >> 2, u0 = li0 & 3;
        int li1 = 512 + tid,  r1 = li1 >> 2, u1 = li1 & 3;
        srcoff0 = (size_t)r0 * K + ((u0 ^ ((r0 >> 1) & 3)) << 3);  ldsoff0 = li0 * 8;
        srcoff1 = (size_t)r1 * K + ((u1 ^ ((r1 >> 1) & 3)) << 3);  ldsoff1 = li1 * 8;
    }

#define STAGE8(ab, ks, ktile, buf) { \
    const bf16* gb_ = ((ab) ? Bbase : Abase) + (ktile) * 64 + (ks) * 32; \
    bf16* lb_ = &lds[buf][ab][ks][0]; \
    gload16(gb_ + srcoff0, lb_ + ldsoff0); \
    gload16(gb_ + srcoff1, lb_ + ldsoff1); }

#define RD_A8(dst, P) { _Pragma("unroll") \
    for (int i_ = 0; i_ < 8; i_++) { \
        int row_ = wm * 128 + i_ * 16 + lc; \
        dst[i_] = *(const bf16x8*)((P) + row_ * 32 + ((lg ^ ((row_ >> 1) & 3)) << 3)); } }
#define RD_B4(dst, P) { _Pragma("unroll") \
    for (int fc_ = 0; fc_ < 4; fc_++) { \
        int row_ = wn * 64 + fc_ * 16 + lc; \
        dst[fc_] = *(const bf16x8*)((P) + row_ * 32 + ((lg ^ ((row_ >> 1) & 3)) << 3)); } }
#define MM32(Av, Bv) { _Pragma("unroll") \
    for (int i_ = 0; i_ < 8; i_++) _Pragma("unroll") \
        for (int fc_ = 0; fc_ < 4; fc_++) \
            acc[i_][fc_] = __builtin_amdgcn_mfma_f32_16x16x32_bf16(Av[i_], Bv[fc_], acc[i_][fc_], 0, 0, 0); }
#define BAR() { __builtin_amdgcn_s_barrier(); asm volatile("" ::: "memory"); }

    f32x4 acc[8][4] = {};
    bf16x8 aX[8], bX[4], aY[8], bY[4];

    // prologue: tile 0 -> buf 0; drain; pre-read X = ks0(buf0)
    STAGE8(0, 0, 0, 0); STAGE8(1, 0, 0, 0); STAGE8(0, 1, 0, 0); STAGE8(1, 1, 0, 0);
    asm volatile("s_waitcnt vmcnt(0)" ::: "memory");
    BAR();
    RD_A8(aX, &lds[0][0][0][0]);
    RD_B4(bX, &lds[0][1][0][0]);

    for (int kt = 0; kt < NT; ++kt) {
        const int cur = kt & 1, nxt = cur ^ 1;
        const bool notlast = (kt + 1 < NT);
        // stage tile t+1 (8 vm loads/thread); then read Y = ks1(cur) — both covered by MM(X)
        if (notlast) {
            STAGE8(0, 0, kt + 1, nxt); STAGE8(1, 0, kt + 1, nxt);
            STAGE8(0, 1, kt + 1, nxt); STAGE8(1, 1, kt + 1, nxt);
        }
        RD_A8(aY, &lds[cur][0][1][0]);
        RD_B4(bY, &lds[cur][1][1][0]);
        __builtin_amdgcn_s_setprio(1);
        MM32(aX, bX);
        __builtin_amdgcn_s_setprio(0);
        if (notlast) {
            asm volatile("s_waitcnt lgkmcnt(0)" ::: "memory");  // Y in regs -> cur free for rewrite
            asm volatile("s_waitcnt vmcnt(0)" ::: "memory");    // own stage writes to nxt landed
            BAR();                                              // publish nxt, free cur
            RD_A8(aX, &lds[nxt][0][0][0]);                      // covered by MM(Y)
            RD_B4(bX, &lds[nxt][1][0][0]);
        } else {
            asm volatile("s_waitcnt lgkmcnt(0)" ::: "memory");
        }
        __builtin_amdgcn_s_setprio(1);
        MM32(aY, bY);
        __builtin_amdgcn_s_setprio(0);
    }
#undef STAGE8
#undef RD_A8
#undef RD_B4
#undef MM32
#undef BAR
    // epilogue: D row = (lane>>4)*4 + reg, col = lane&15  [m89/m91]
#pragma unroll
    for (int m = 0; m < 8; m++)
#pragma unroll
        for (int fc = 0; fc < 4; fc++)
#pragma unroll
            for (int j = 0; j < 4; j++) {
                int r = row0 + wm * 128 + m * 16 + lg * 4 + j;
                int c = col0 + wn * 64 + fc * 16 + lc;
                C[(size_t)r * N + c] = (bf16)acc[m][fc][j];
            }
}

// ================= 128x128 8-wave phase-pipelined GEMM (out-projection, fp32 out + bias) =================
__global__ __launch_bounds__(512, 2) void k_gemmO(const bf16* __restrict__ A, const bf16* __restrict__ Bt,
                                                  float* __restrict__ C, const float* __restrict__ bias,
                                                  int N, int K) {
    __shared__ __align__(16) bf16 lds[2][2][2][128 * 32];  // [buf][A/B][ks][slice] = 64 KiB
    const int tid = threadIdx.x;
    const int l = tid & 63, wid = tid >> 6;
    const int lg = l >> 4, lc = l & 15;
    const int wm = wid >> 2, wn = wid & 3;          // 2x4 wave grid; wave owns 64x32
    const int bid = blockIdx.x;
    const int xcd = bid & 7, g = bid >> 3;
    const int rt = g & 15, ct = xcd * 2 + (g >> 4); // 16 row-tiles, 2 col-panels per XCD
    const int row0 = rt * 128, col0 = ct * 128;
    const int NT = K >> 6;

    const bf16* Abase = A  + (size_t)row0 * K;
    const bf16* Bbase = Bt + (size_t)col0 * K;

    size_t srcoff; int ldsoff;
    {
        int r0 = tid >> 2, u0 = tid & 3;
        srcoff = (size_t)r0 * K + ((u0 ^ ((r0 >> 1) & 3)) << 3);
        ldsoff = tid * 8;
    }

#define STAGEO(ab, ks, ktile, buf) { \
    const bf16* gb_ = ((ab) ? Bbase : Abase) + (ktile) * 64 + (ks) * 32; \
    gload16(gb_ + srcoff, &lds[buf][ab][ks][0] + ldsoff); }

    f32x4 acc[4][2] = {};

    STAGEO(0, 0, 0, 0); STAGEO(1, 0, 0, 0); STAGEO(0, 1, 0, 0); STAGEO(1, 1, 0, 0);
    asm volatile("s_waitcnt vmcnt(2)" ::: "memory");
    __builtin_amdgcn_s_barrier();
    asm volatile("" ::: "memory");

    for (int kt = 0; kt < NT; ++kt) {
        const int cur = kt & 1, nxt = cur ^ 1;
        const bool notlast = (kt + 1 < NT);
#pragma unroll
        for (int ph = 0; ph < 2; ph++) {
            const bf16* As_ = &lds[cur][0][ph][0];
            const bf16* Bs_ = &lds[cur][1][ph][0];
            bf16x8 aF[4], bB[2];
#pragma unroll
            for (int n = 0; n < 2; n++) {
                int row = wn * 32 + n * 16 + lc;
                bB[n] = *(const bf16x8*)(Bs_ + row * 32 + ((lg ^ ((row >> 1) & 3)) << 3));
            }
#pragma unroll
            for (int m = 0; m < 4; m++) {
                int row = wm * 64 + m * 16 + lc;
                aF[m] = *(const bf16x8*)(As_ + row * 32 + ((lg ^ ((row >> 1) & 3)) << 3));
            }
            if (notlast) {
                if (ph == 0) { STAGEO(0, 0, kt + 1, nxt); STAGEO(1, 0, kt + 1, nxt); }
                else         { STAGEO(0, 1, kt + 1, nxt); STAGEO(1, 1, kt + 1, nxt); }
            }
            __builtin_amdgcn_s_barrier();
            asm volatile("" ::: "memory");
            __builtin_amdgcn_s_setprio(1);
#pragma unroll
            for (int m = 0; m < 4; m++)
#pragma unroll
                for (int n = 0; n < 2; n++)
                    acc[m][n] = __builtin_amdgcn_mfma_f32_16x16x32_bf16(aF[m], bB[n], acc[m][n], 0, 0, 0);
            __builtin_amdgcn_s_setprio(0);
            if (notlast)          asm volatile("s_waitcnt vmcnt(2)" ::: "memory");
            else if (ph == 0)     asm volatile("s_waitcnt vmcnt(0)" ::: "memory");
            __builtin_amdgcn_s_barrier();
            asm volatile("" ::: "memory");
        }
    }
#undef STAGEO
#pragma unroll
    for (int m = 0; m < 4; m++)
#pragma unroll
        for (int n = 0; n < 2; n++)
#pragma unroll
            for (int j = 0; j < 4; j++) {
                int r = row0 + wm * 64 + m * 16 + lg * 4 + j;
                int c = col0 + wn * 32 + n * 16 + lc;
                C[(size_t)r * N + c] = acc[m][n][j] + bias[c];
            }
}

// ---------------- flash attention: K/V cooperatively LDS-staged, pipelined ----------------
__global__ __launch_bounds__(256, 3) void k_attn(const bf16* __restrict__ qkv, const bf16* __restrict__ vT,
                                                 bf16* __restrict__ cv) {
    const int bid = blockIdx.x;
    const int xcd = bid & 7, g = bid >> 3;
    const int qt = (g & 32) ? (g & 15) : (15 - (g & 15));  // balanced pairing
    const int bh = xcd + 8 * (g >> 4);     // all q-tiles of a bh pinned to one XCD
    const int b = bh >> 4, h = bh & 15;
    const int tid = threadIdx.x, l = tid & 63, w = tid >> 6;
    const int lg = l >> 4, lc = l & 15;
    __shared__ __align__(16) bf16 Ks[64 * 192];     // 24576 B
    __shared__ __align__(16) bf16 Vs[128 * 64];     // 16384 B
    __shared__ __align__(16) bf16 Pl[4][16][72];    //  9216 B
    const bf16* Qb = qkv + (size_t)b * Sc * NCAT + h * QKDc;
    const bf16* Kb = Qb + NQ;
    const bf16* Vt = vT + (size_t)bh * 128 * Sc;    // [128][1024]

    int sK[6];
#pragma unroll
    for (int r = 0; r < 6; r++) {
        int li = r * 256 + tid;
        int row = li / 24, c16 = li - row * 24;
        sK[r] = row * NCAT + ((c16 ^ (row & 7)) * 8);
    }
    int sV[4];
#pragma unroll
    for (int r = 0; r < 4; r++) {
        int li = r * 256 + tid;
        int row = li >> 3, c16 = li & 7;
        sV[r] = row * Sc + ((c16 ^ (row & 7)) * 8);
    }
    const int swz = lc & 7;

    bf16x8 qF[6];
    const int qrow = qt * 64 + w * 16 + lc;
#pragma unroll
    for (int kc = 0; kc < 6; kc++) qF[kc] = *(const bf16x8*)(Qb + (size_t)qrow * NCAT + kc * 32 + lg * 8);

    f32x4 acc[8] = {};
    float mrow[4] = {-1e30f, -1e30f, -1e30f, -1e30f};
    float lsum[4] = {0.f, 0.f, 0.f, 0.f};
    const float scale = 0.07216878364870323f;  // 192^-0.5

#pragma unroll
    for (int r = 0; r < 6; r++) gload16(Kb + sK[r], Ks + (r * 256 + tid) * 8);

    for (int c = 0; c <= qt; ++c) {
        const int t0 = c * 64;
        __syncthreads();   // B1: drains vmcnt -> K[c] staged
#pragma unroll
        for (int r = 0; r < 4; r++) gload16(Vt + t0 + sV[r], Vs + (r * 256 + tid) * 8);
        f32x4 sc[4] = {};
#pragma unroll
        for (int nt = 0; nt < 4; nt++)
#pragma unroll
            for (int kc = 0; kc < 6; kc++) {
                bf16x8 kf = *(const bf16x8*)(Ks + (nt * 16 + lc) * 192 + (((kc * 4 + lg) ^ swz) * 8));
                sc[nt] = __builtin_amdgcn_mfma_f32_16x16x32_bf16(qF[kc], kf, sc[nt], 0, 0, 0);
            }
        __syncthreads();   // B2: K[c] reads done; drains vmcnt -> V[c] staged
        if (c < qt) {
#pragma unroll
            for (int r = 0; r < 6; r++) gload16(Kb + (size_t)(t0 + 64) * NCAT + sK[r], Ks + (r * 256 + tid) * 8);
        }
        float p[4][4];
        float cmax[4] = {-1e30f, -1e30f, -1e30f, -1e30f};
        const bool diag = (c == qt);
#pragma unroll
        for (int nt = 0; nt < 4; nt++)
#pragma unroll
            for (int j = 0; j < 4; j++) {
                float v = sc[nt][j] * scale;
                if (diag) {
                    int tg = t0 + nt * 16 + lc;
                    int rg = qt * 64 + w * 16 + lg * 4 + j;
                    if (tg > rg) v = -1e9f;
                }
                p[nt][j] = v;
                cmax[j] = fmaxf(cmax[j], v);
            }
#pragma unroll
        for (int j = 0; j < 4; j++)
#pragma unroll
            for (int d = 1; d < 16; d <<= 1) cmax[j] = fmaxf(cmax[j], __shfl_xor(cmax[j], d));
        float f[4];
#pragma unroll
        for (int j = 0; j < 4; j++) {
            float nm = fmaxf(mrow[j], cmax[j]);
            f[j] = __expf(mrow[j] - nm);
            mrow[j] = nm;
        }
        float psum[4] = {0.f, 0.f, 0.f, 0.f};
#pragma unroll
        for (int nt = 0; nt < 4; nt++)
#pragma unroll
            for (int j = 0; j < 4; j++) {
                p[nt][j] = __expf(p[nt][j] - mrow[j]);
                psum[j] += p[nt][j];
            }
#pragma unroll
        for (int j = 0; j < 4; j++) {
#pragma unroll
            for (int d = 1; d < 16; d <<= 1) psum[j] += __shfl_xor(psum[j], d);
            lsum[j] = lsum[j] * f[j] + psum[j];
        }
#pragma unroll
        for (int n = 0; n < 8; n++)
#pragma unroll
            for (int j = 0; j < 4; j++) acc[n][j] *= f[j];
#pragma unroll
        for (int nt = 0; nt < 4; nt++)
#pragma unroll
            for (int j = 0; j < 4; j++)
                Pl[w][lg * 4 + j][nt * 16 + lc] = (bf16)p[nt][j];
#pragma unroll
        for (int ks = 0; ks < 2; ks++) {
            bf16x8 aP = *(const bf16x8*)(&Pl[w][lc][ks * 32 + lg * 8]);
#pragma unroll
            for (int n = 0; n < 8; n++) {
                bf16x8 bV = *(const bf16x8*)(Vs + (n * 16 + lc) * 64 + (((ks * 4 + lg) ^ swz) * 8));
                acc[n] = __builtin_amdgcn_mfma_f32_16x16x32_bf16(aP, bV, acc[n], 0, 0, 0);
            }
        }
    }
#pragma unroll
    for (int j = 0; j < 4; j++) {
        float inv = 1.0f / lsum[j];
        int r = qt * 64 + w * 16 + lg * 4 + j;
#pragma unroll
        for (int n = 0; n < 8; n++) {
            float v = acc[n][j] * inv;
            cv[((size_t)(b * Sc + r) * Hc + h) * VDc + n * 16 + lc] = (bf16)v;
        }
    }
}

// ---------------- launch ----------------
extern "C" void kernel_launch(void* const* d_in, const int* in_sizes, int n_in,
                              void* d_out, int out_size, void* d_ws, size_t ws_size,
                              hipStream_t stream) {
    const float* x  = (const float*)d_in[0];
    const float* Wq = (const float*)d_in[1];
    const float* Wk = (const float*)d_in[2];
    const float* Wv = (const float*)d_in[3];
    const float* Wo = (const float*)d_in[4];
    const float* bo = (const float*)d_in[5];
    float* out = (float*)d_out;
    char* ws = (char*)d_ws;

    // workspace layout (bytes)
    bf16*  wcat = (bf16*)(ws + 0);           // 8192x2048 bf16 = 33554432
    bf16*  woT  = (bf16*)(ws + 33554432);    // 2048x2048 bf16 =  8388608
    bf16*  xb   = (bf16*)(ws + 41943040);    // 2048x2048 bf16 =  8388608
    bf16*  qkvb = (bf16*)(ws + 50331648);    // 2048x8192 bf16 = 33554432
    bf16*  cvb  = (bf16*)(ws + 83886080);    // 2048x2048 bf16 =  8388608
    bf16*  vTb  = (bf16*)(ws + 92274688);    // 32x128x1024 bf16 = 8388608
    float* cosT = (float*)(ws + 100663296);  // 1024x32 f32    =   131072
    float* sinT = (float*)(ws + 100794368);  // 1024x32 f32    =   131072

    k_prep<<<dim3(32, 225), 256, 0, stream>>>(x, Wq, Wk, Wv, Wo, xb, wcat, woT, cosT, sinT);
    // fused QKV projection: (2048x2048) x (8192x2048)^T -> (2048x8192) bf16
    k_gemm8<<<256, 512, 0, stream>>>(xb, wcat, qkvb, NCAT, DIMc, NCAT / 256);
    k_ropevt<<<3072, 256, 0, stream>>>(qkvb, cosT, sinT, vTb); // rope Q+K, and V^T
    k_attn<<<512, 256, 0, stream>>>(qkvb, vTb, cvb);
    // output projection with bias: (2048x2048) x (2048x2048)^T -> fp32 out
    k_gemmO<<<256, 512, 0, stream>>>(cvb, woT, out, bo, DIMc, DIMc);
}